// Round 10
// baseline (476.185 us; speedup 1.0000x reference)
//
#include <hip/hip_runtime.h>
#include <stdint.h>

typedef short bf16x8_t __attribute__((ext_vector_type(8)));
typedef short bf16x4_t __attribute__((ext_vector_type(4)));
typedef float f32x4_t __attribute__((ext_vector_type(4)));
typedef float f32x16_t __attribute__((ext_vector_type(16)));
typedef unsigned short u16x4_t __attribute__((ext_vector_type(4)));
typedef unsigned short u16x8_t __attribute__((ext_vector_type(8)));

#define DEV static __device__ __forceinline__

DEV float bf2f(unsigned short u) {
  union { unsigned int i; float f; } v; v.i = ((unsigned int)u) << 16; return v.f;
}
DEV unsigned short f2bf(float f) {
  union { float f; unsigned int i; } v; v.f = f;
  unsigned int x = v.i;
  unsigned int lsb = (x >> 16) & 1u;
  x += 0x7fffu + lsb;
  return (unsigned short)(x >> 16);
}

// Up to 3 cvt segments; boundaries in blocks of 256 vec4s (block-uniform).
struct CvtSeg {
  const float* src[3];
  unsigned short* dst[3];
  int bstart[4];   // bstart[0]=0; bstart[3]=total blocks
};

DEV void cvt_block(const CvtSeg& cs, int vb, int tid) {
  int seg = (vb >= cs.bstart[1] ? 1 : 0) + (vb >= cs.bstart[2] ? 1 : 0);
  int local = (vb - cs.bstart[seg]) * 256 + tid;
  float4 v = ((const float4*)cs.src[seg])[local];
  u16x4_t o = { f2bf(v.x), f2bf(v.y), f2bf(v.z), f2bf(v.w) };
  *(u16x4_t*)&cs.dst[seg][local * 4] = o;
}

// ---------------------------------------------------------------------------
// Dispatch 1: convert Wm0 + U0 only (critical path for xu_fused / hyper-0)
__global__ __launch_bounds__(256) void k_cvt(CvtSeg cs) {
  cvt_block(cs, blockIdx.x, threadIdx.x);
}

// ---------------------------------------------------------------------------
// xu_fused: converts x (fp32 -> bf16 in xb) AND computes u0 = x @ U0^T.
__global__ __launch_bounds__(256, 2) void xu_fused(
    const float* __restrict__ x,            // [8192 x 1024] fp32
    const unsigned short* __restrict__ U0,  // [64 x 1024] bf16
    unsigned short* __restrict__ xb,        // [8192 x 1024] bf16 out
    unsigned short* __restrict__ u_out) {   // [8192 x 64] bf16 out
  __shared__ unsigned short tlds[4 * 16 * 72];  // per-wave x chunk [16][72]
  __shared__ float upart[4 * 16 * 68];          // per-wave u partial [16][68]

  const int tid = threadIdx.x;
  const int lane = tid & 63;
  const int w = tid >> 6;
  const int fr = lane & 15;
  const int quad = lane >> 4;
  const int rowBase = blockIdx.x * 16;

  unsigned short* tl = &tlds[w * 16 * 72];
  const int m2 = lane >> 2;          // row within the 16-row block
  const int kc = (lane & 3) * 16;    // 16-col sub-chunk

  f32x4_t uacc[4];
#pragma unroll
  for (int n = 0; n < 4; n++) uacc[n] = f32x4_t{0.f, 0.f, 0.f, 0.f};

  for (int it = 0; it < 4; ++it) {
    const int cb = w * 256 + it * 64;  // k-chunk base

    // load x[16][64] fp32 chunk, convert, stage to LDS + store xb
    {
      const float* xp = x + (size_t)(rowBase + m2) * 1024 + cb + kc;
      float4 v0 = *(const float4*)(xp);
      float4 v1 = *(const float4*)(xp + 4);
      float4 v2 = *(const float4*)(xp + 8);
      float4 v3 = *(const float4*)(xp + 12);
      u16x8_t o0 = { f2bf(v0.x), f2bf(v0.y), f2bf(v0.z), f2bf(v0.w),
                     f2bf(v1.x), f2bf(v1.y), f2bf(v1.z), f2bf(v1.w) };
      u16x8_t o1 = { f2bf(v2.x), f2bf(v2.y), f2bf(v2.z), f2bf(v2.w),
                     f2bf(v3.x), f2bf(v3.y), f2bf(v3.z), f2bf(v3.w) };
      *(u16x8_t*)&tl[m2 * 72 + kc] = o0;
      *(u16x8_t*)&tl[m2 * 72 + kc + 8] = o1;
      unsigned short* xo = xb + (size_t)(rowBase + m2) * 1024 + cb + kc;
      *(u16x8_t*)xo = o0;
      *(u16x8_t*)(xo + 8) = o1;
    }

    // u += x_chunk @ U0^T (K = this 64-col chunk)
#pragma unroll
    for (int ks = 0; ks < 2; ++ks) {
      bf16x8_t at = *(const bf16x8_t*)&tl[fr * 72 + ks * 32 + quad * 8];
#pragma unroll
      for (int n = 0; n < 4; n++) {
        bf16x8_t bu = *(const bf16x8_t*)&U0[(size_t)(n * 16 + fr) * 1024 + cb +
                                            ks * 32 + quad * 8];
        uacc[n] = __builtin_amdgcn_mfma_f32_16x16x32_bf16(at, bu, uacc[n], 0, 0, 0);
      }
    }
  }

  // cross-wave reduction of u partials
  {
    float* up = &upart[w * 16 * 68];
#pragma unroll
    for (int n = 0; n < 4; n++)
#pragma unroll
      for (int r = 0; r < 4; r++)
        up[(quad * 4 + r) * 68 + n * 16 + fr] = uacc[n][r];
  }
  __syncthreads();
  {
    int m = tid >> 4;
    int c0 = (tid & 15) * 4;
    f32x4_t s = {0.f, 0.f, 0.f, 0.f};
#pragma unroll
    for (int wv = 0; wv < 4; wv++)
      s += *(const f32x4_t*)&upart[wv * 16 * 68 + m * 68 + c0];
    u16x4_t o = { f2bf(s[0]), f2bf(s[1]), f2bf(s[2]), f2bf(s[3]) };
    *(u16x4_t*)&u_out[(size_t)(rowBase + m) * 64 + c0] = o;
  }
}

// ---------------------------------------------------------------------------
// Fused hyper-GEMM + per-sample contraction (col' = s*64+r permutation),
// PLUS appended cvt blocks (blockIdx.x >= 2048).
// ROUND 10: MFMA shape switched 16x16x32 -> 32x32x16 (15% better FLOP/cyc,
// m06/m119). A/B frag: lane = m + 32*(k/8), k=(lane>>5)*8+j. C/D (m74/m101):
// col=lane&31, row=(reg&3)+8*(reg>>2)+4*(lane>>5). Same LDS bytes + swizzle.
__global__ __launch_bounds__(256, 2) void k_hyper(
    const unsigned short* __restrict__ A,    // [8192 x 1024] bf16
    const unsigned short* __restrict__ Wmb,  // [4096 x 1024] bf16
    const unsigned short* __restrict__ ug,   // [8192 x 64] bf16
    const float* __restrict__ bm,            // [4096] fp32
    unsigned short* __restrict__ h_out,      // [8192 x 64] bf16
    CvtSeg cs) {
  __shared__ unsigned short smem[16384];

  if (blockIdx.x >= 2048) {                  // appended conversion work
    cvt_block(cs, blockIdx.x - 2048, threadIdx.x);
    return;
  }

  unsigned short* As = smem;
  unsigned short* Bs = smem + 8192;
  const int K = 1024;

  const int tid = threadIdx.x;
  const int lane = tid & 63;
  const int w = tid >> 6;
  const int wrow0 = (w & 1) * 64;
  const int wcol0 = (w >> 1) * 64;
  const int bx = blockIdx.x & 31;
  const int by = blockIdx.x >> 5;
  const int rowBase = by * 128;
  const int colBase = bx * 128;

  const int rl = lane >> 3;
  const int kbg = (lane & 7) ^ rl;
  const int c31 = lane & 31;      // row/col within 32-frag
  const int hi = lane >> 5;       // k-half selector

  f32x16_t acc[2][2];
#pragma unroll
  for (int i = 0; i < 2; i++)
#pragma unroll
    for (int j = 0; j < 2; j++)
#pragma unroll
      for (int v = 0; v < 16; v++) acc[i][j][v] = 0.f;

  for (int kt = 0; kt < K; kt += 64) {
    __syncthreads();
#pragma unroll
    for (int jj = 0; jj < 4; ++jj) {
      int tr = w * 32 + jj * 8 + rl;
      int ct = colBase + tr;
      int pr = ((ct & 63) << 6) | (ct >> 6);  // Wm row for hyper-col ct
      const unsigned short* ga = A + (size_t)(rowBase + tr) * K + kt + kbg * 8;
      const unsigned short* gb = Wmb + (size_t)pr * K + kt + kbg * 8;
      __builtin_amdgcn_global_load_lds(
          (const __attribute__((address_space(1))) void*)ga,
          (__attribute__((address_space(3))) void*)&As[(w * 32 + jj * 8) * 64],
          16, 0, 0);
      __builtin_amdgcn_global_load_lds(
          (const __attribute__((address_space(1))) void*)gb,
          (__attribute__((address_space(3))) void*)&Bs[(w * 32 + jj * 8) * 64],
          16, 0, 0);
    }
    __syncthreads();

    // 4 ksteps of 16; per kstep: 2 A-frags + 2 B-frags, 4 MFMAs
#pragma unroll
    for (int t = 0; t < 4; ++t) {
      const int kb = t * 2 + hi;   // 8-elem k-group this lane reads
      bf16x8_t a[2], b[2];
#pragma unroll
      for (int i = 0; i < 2; i++) {
        int m = wrow0 + i * 32 + c31;
        int slot = kb ^ (m & 7);
        a[i] = *(const bf16x8_t*)&As[m * 64 + slot * 8];
      }
#pragma unroll
      for (int j = 0; j < 2; j++) {
        int n = wcol0 + j * 32 + c31;
        int slot = kb ^ (n & 7);
        b[j] = *(const bf16x8_t*)&Bs[n * 64 + slot * 8];
      }
#pragma unroll
      for (int i = 0; i < 2; i++)
#pragma unroll
        for (int j = 0; j < 2; j++)
          acc[i][j] = __builtin_amdgcn_mfma_f32_32x32x16_bf16(a[i], b[j],
                                                              acc[i][j], 0, 0, 0);
    }
  }

  // ---- fused contraction epilogue ----
  __syncthreads();

  // stage u transposed: u_t[r][row], stride 136 to spread banks
  {
    int row = tid >> 1;
    int c0 = (tid & 1) * 32;
    const unsigned short* up = ug + (size_t)(rowBase + row) * 64 + c0;
    bf16x8_t v0 = *(const bf16x8_t*)(up);
    bf16x8_t v1 = *(const bf16x8_t*)(up + 8);
    bf16x8_t v2 = *(const bf16x8_t*)(up + 16);
    bf16x8_t v3 = *(const bf16x8_t*)(up + 24);
#pragma unroll
    for (int m = 0; m < 8; m++) {
      smem[(c0 + m) * 136 + row] = (unsigned short)v0[m];
      smem[(c0 + 8 + m) * 136 + row] = (unsigned short)v1[m];
      smem[(c0 + 16 + m) * 136 + row] = (unsigned short)v2[m];
      smem[(c0 + 24 + m) * 136 + row] = (unsigned short)v3[m];
    }
  }
  __syncthreads();

  const int s = bx * 2 + (w >> 1);   // this wave's s value
  // bm for this lane's two r values: r_j = j*32 + c31
  float bmv[2];
#pragma unroll
  for (int j = 0; j < 2; j++) bmv[j] = bm[(j * 32 + c31) * 64 + s];

#pragma unroll
  for (int i = 0; i < 2; i++) {
#pragma unroll
    for (int vg = 0; vg < 4; vg++) {
      int rowb = wrow0 + i * 32 + 8 * vg + 4 * hi;  // 4 consecutive rows
      bf16x4_t uv[2];
#pragma unroll
      for (int j = 0; j < 2; j++)
        uv[j] = *(const bf16x4_t*)&smem[(j * 32 + c31) * 136 + rowb];
#pragma unroll
      for (int r4 = 0; r4 < 4; r4++) {
        int v = vg * 4 + r4;
        float p = bf2f((unsigned short)uv[0][r4]) * (acc[i][0][v] + bmv[0]) +
                  bf2f((unsigned short)uv[1][r4]) * (acc[i][1][v] + bmv[1]);
        p += __shfl_xor(p, 1, 64);
        p += __shfl_xor(p, 2, 64);
        p += __shfl_xor(p, 4, 64);
        p += __shfl_xor(p, 8, 64);
        p += __shfl_xor(p, 16, 64);
        if (c31 == 0)
          h_out[(size_t)(rowBase + rowb + r4) * 64 + s] = f2bf(p);
      }
    }
  }
}

// ---------------------------------------------------------------------------
// Fused V-GEMM + next-layer u-GEMM (r4-proven).
__global__ __launch_bounds__(256, 2) void vu_fused(
    const unsigned short* __restrict__ h,    // [8192 x 64] bf16
    const unsigned short* __restrict__ Vb,   // [1024 x 64] bf16
    const float* __restrict__ bias,          // [1024] fp32
    const unsigned short* __restrict__ Un,   // [64 x 1024] bf16 (next U)
    unsigned short* __restrict__ act,        // [8192 x 1024] bf16
    unsigned short* __restrict__ u_out) {    // [8192 x 64] bf16
  __shared__ unsigned short tlds[4 * 16 * 72];
  __shared__ float upart[4 * 16 * 68];

  const int tid = threadIdx.x;
  const int lane = tid & 63;
  const int w = tid >> 6;
  const int fr = lane & 15;
  const int quad = lane >> 4;
  const int rowBase = blockIdx.x * 16;

  unsigned short* tl = &tlds[w * 16 * 72];

  bf16x8_t ah0 = *(const bf16x8_t*)&h[(size_t)(rowBase + fr) * 64 + quad * 8];
  bf16x8_t ah1 = *(const bf16x8_t*)&h[(size_t)(rowBase + fr) * 64 + 32 + quad * 8];

  f32x4_t uacc[4];
#pragma unroll
  for (int n = 0; n < 4; n++) uacc[n] = f32x4_t{0.f, 0.f, 0.f, 0.f};

  for (int it = 0; it < 4; ++it) {
    const int cb = w * 256 + it * 64;

    f32x4_t tacc[4];
#pragma unroll
    for (int nt = 0; nt < 4; nt++) {
      const unsigned short* vrow = Vb + (size_t)(cb + nt * 16 + fr) * 64;
      bf16x8_t b0 = *(const bf16x8_t*)&vrow[quad * 8];
      bf16x8_t b1 = *(const bf16x8_t*)&vrow[32 + quad * 8];
      f32x4_t z = {0.f, 0.f, 0.f, 0.f};
      z = __builtin_amdgcn_mfma_f32_16x16x32_bf16(ah0, b0, z, 0, 0, 0);
      tacc[nt] = __builtin_amdgcn_mfma_f32_16x16x32_bf16(ah1, b1, z, 0, 0, 0);
    }

#pragma unroll
    for (int nt = 0; nt < 4; nt++) {
      float bv = bias[cb + nt * 16 + fr];
#pragma unroll
      for (int r = 0; r < 4; r++) {
        float v = tacc[nt][r] + bv;
        v = v > 0.f ? v : 0.f;
        tl[(quad * 4 + r) * 72 + nt * 16 + fr] = f2bf(v);
      }
    }

    {
      int m2 = lane >> 2;
      int kc = (lane & 3) * 16;
      bf16x8_t t0 = *(const bf16x8_t*)&tl[m2 * 72 + kc];
      bf16x8_t t1 = *(const bf16x8_t*)&tl[m2 * 72 + kc + 8];
      unsigned short* ap = act + (size_t)(rowBase + m2) * 1024 + cb + kc;
      *(bf16x8_t*)ap = t0;
      *(bf16x8_t*)(ap + 8) = t1;
    }

#pragma unroll
    for (int ks = 0; ks < 2; ++ks) {
      bf16x8_t at = *(const bf16x8_t*)&tl[fr * 72 + ks * 32 + quad * 8];
#pragma unroll
      for (int n = 0; n < 4; n++) {
        bf16x8_t bu = *(const bf16x8_t*)&Un[(size_t)(n * 16 + fr) * 1024 + cb +
                                            ks * 32 + quad * 8];
        uacc[n] = __builtin_amdgcn_mfma_f32_16x16x32_bf16(at, bu, uacc[n], 0, 0, 0);
      }
    }
  }

  {
    float* up = &upart[w * 16 * 68];
#pragma unroll
    for (int n = 0; n < 4; n++)
#pragma unroll
      for (int r = 0; r < 4; r++)
        up[(quad * 4 + r) * 68 + n * 16 + fr] = uacc[n][r];
  }
  __syncthreads();
  {
    int m = tid >> 4;
    int c0 = (tid & 15) * 4;
    f32x4_t s = {0.f, 0.f, 0.f, 0.f};
#pragma unroll
    for (int wv = 0; wv < 4; wv++)
      s += *(const f32x4_t*)&upart[wv * 16 * 68 + m * 68 + c0];
    u16x4_t o = { f2bf(s[0]), f2bf(s[1]), f2bf(s[2]), f2bf(s[3]) };
    *(u16x4_t*)&u_out[(size_t)(rowBase + m) * 64 + c0] = o;
  }
}

// ---------------------------------------------------------------------------
// Final layer: out = h @ V^T + b (fp32), K = 64.
__global__ __launch_bounds__(256, 2) void k_final(
    const unsigned short* __restrict__ A, const unsigned short* __restrict__ B,
    const float* __restrict__ bias, float* __restrict__ Cout) {
  __shared__ unsigned short As[128 * 64];
  __shared__ unsigned short Bs[128 * 64];

  const int tid = threadIdx.x;
  const int lane = tid & 63;
  const int w = tid >> 6;
  const int wrow0 = (w & 1) * 64;
  const int wcol0 = (w >> 1) * 64;
  const int rowBase = blockIdx.y * 128;
  const int colBase = blockIdx.x * 128;

  const int rl = lane >> 3;
  const int kbg = (lane & 7) ^ rl;
  const int fr = lane & 15;
  const int quad = lane >> 4;

  f32x4_t acc[4][4];
#pragma unroll
  for (int i = 0; i < 4; i++)
#pragma unroll
    for (int j = 0; j < 4; j++) acc[i][j] = f32x4_t{0.f, 0.f, 0.f, 0.f};

  __syncthreads();
#pragma unroll
  for (int jj = 0; jj < 4; ++jj) {
    int tr = w * 32 + jj * 8 + rl;
    const unsigned short* ga = A + (size_t)(rowBase + tr) * 64 + kbg * 8;
    const unsigned short* gb = B + (size_t)(colBase + tr) * 64 + kbg * 8;
    __builtin_amdgcn_global_load_lds(
        (const __attribute__((address_space(1))) void*)ga,
        (__attribute__((address_space(3))) void*)&As[(w * 32 + jj * 8) * 64],
        16, 0, 0);
    __builtin_amdgcn_global_load_lds(
        (const __attribute__((address_space(1))) void*)gb,
        (__attribute__((address_space(3))) void*)&Bs[(w * 32 + jj * 8) * 64],
        16, 0, 0);
  }
  __syncthreads();

#pragma unroll
  for (int ks = 0; ks < 2; ++ks) {
    bf16x8_t a[4], b[4];
#pragma unroll
    for (int i = 0; i < 4; i++) {
      int m = wrow0 + i * 16 + fr;
      int slot = (ks * 4 + quad) ^ (m & 7);
      a[i] = *(const bf16x8_t*)&As[m * 64 + slot * 8];
    }
#pragma unroll
    for (int j = 0; j < 4; j++) {
      int n = wcol0 + j * 16 + fr;
      int slot = (ks * 4 + quad) ^ (n & 7);
      b[j] = *(const bf16x8_t*)&Bs[n * 64 + slot * 8];
    }
#pragma unroll
    for (int i = 0; i < 4; i++)
#pragma unroll
      for (int j = 0; j < 4; j++)
        acc[i][j] = __builtin_amdgcn_mfma_f32_16x16x32_bf16(a[i], b[j],
                                                            acc[i][j], 0, 0, 0);
  }

#pragma unroll
  for (int j = 0; j < 4; j++) {
    int col = colBase + wcol0 + j * 16 + fr;
    float bv = bias[col];
#pragma unroll
    for (int i = 0; i < 4; i++) {
#pragma unroll
      for (int r = 0; r < 4; r++) {
        int row = rowBase + wrow0 + i * 16 + quad * 4 + r;
        Cout[(size_t)row * 1024 + col] = acc[i][j][r] + bv;
      }
    }
  }
}

// ---------------------------------------------------------------------------
extern "C" void kernel_launch(void* const* d_in, const int* in_sizes, int n_in,
                              void* d_out, int out_size, void* d_ws,
                              size_t ws_size, hipStream_t stream) {
  const float* x = (const float*)d_in[0];
  const float* Wm[3] = {(const float*)d_in[1], (const float*)d_in[6], (const float*)d_in[11]};
  const float* bm[3] = {(const float*)d_in[2], (const float*)d_in[7], (const float*)d_in[12]};
  const float* U[3]  = {(const float*)d_in[3], (const float*)d_in[8], (const float*)d_in[13]};
  const float* V[3]  = {(const float*)d_in[4], (const float*)d_in[9], (const float*)d_in[14]};
  const float* bs[3] = {(const float*)d_in[5], (const float*)d_in[10], (const float*)d_in[15]};

  char* p = (char*)d_ws;
  unsigned short* xb = (unsigned short*)p;  p += 8192UL * 1024 * 2;
  unsigned short* act = (unsigned short*)p; p += 8192UL * 1024 * 2;
  unsigned short* Wmb[3];
  for (int l = 0; l < 3; l++) { Wmb[l] = (unsigned short*)p; p += 4096UL * 1024 * 2; }
  unsigned short* Ub[3];
  for (int l = 0; l < 3; l++) { Ub[l] = (unsigned short*)p; p += 64UL * 1024 * 2; }
  unsigned short* Vb[3];
  for (int l = 0; l < 3; l++) { Vb[l] = (unsigned short*)p; p += 1024UL * 64 * 2; }
  unsigned short* hb = (unsigned short*)p;  p += 8192UL * 64 * 2;
  unsigned short* ug = (unsigned short*)p;  p += 8192UL * 64 * 2;

  // Dispatch 1: convert Wm0 + U0 (38 MB read) — the only serial conversions
  CvtSeg c0;
  c0.src[0] = Wm[0]; c0.dst[0] = Wmb[0];
  c0.src[1] = U[0];  c0.dst[1] = Ub[0];
  c0.src[2] = U[0];  c0.dst[2] = Ub[0];   // unused (bstart collapse)
  c0.bstart[0] = 0; c0.bstart[1] = 4096; c0.bstart[2] = 4160; c0.bstart[3] = 4160;
  k_cvt<<<4160, 256, 0, stream>>>(c0);

  // Dispatch 2: x cvt + u0 = x @ U0^T, fused (writes xb and ug)
  xu_fused<<<512, 256, 0, stream>>>(x, Ub[0], xb, ug);

  // cvt tables for the work appended to each hyper dispatch
  CvtSeg ch[3];
  ch[0].src[0] = Wm[1]; ch[0].dst[0] = Wmb[1];
  ch[0].src[1] = U[1];  ch[0].dst[1] = Ub[1];
  ch[0].src[2] = V[0];  ch[0].dst[2] = Vb[0];
  ch[0].bstart[0] = 0; ch[0].bstart[1] = 4096; ch[0].bstart[2] = 4160; ch[0].bstart[3] = 4224;
  ch[1].src[0] = Wm[2]; ch[1].dst[0] = Wmb[2];
  ch[1].src[1] = U[2];  ch[1].dst[1] = Ub[2];
  ch[1].src[2] = V[1];  ch[1].dst[2] = Vb[1];
  ch[1].bstart[0] = 0; ch[1].bstart[1] = 4096; ch[1].bstart[2] = 4160; ch[1].bstart[3] = 4224;
  ch[2].src[0] = V[2]; ch[2].dst[0] = Vb[2];
  ch[2].src[1] = V[2]; ch[2].dst[1] = Vb[2];   // unused
  ch[2].src[2] = V[2]; ch[2].dst[2] = Vb[2];   // unused
  ch[2].bstart[0] = 0; ch[2].bstart[1] = 64; ch[2].bstart[2] = 64; ch[2].bstart[3] = 64;

  const int hyperGrid[3] = {2048 + 4224, 2048 + 4224, 2048 + 64};

  const unsigned short* cur = xb;
  for (int l = 0; l < 3; l++) {
    // fused: h = einsum('br,brs->bs', u, cur@Wm^T + bm)  [+ appended cvt]
    k_hyper<<<hyperGrid[l], 256, 0, stream>>>(cur, Wmb[l], ug, bm[l], hb, ch[l]);
    if (l < 2) {
      // act = relu(h@V^T + b); u(next) = act @ U[l+1]^T
      vu_fused<<<512, 256, 0, stream>>>(hb, Vb[l], bs[l], Ub[l + 1], act, ug);
      cur = act;
    } else {
      k_final<<<dim3(8, 64), 256, 0, stream>>>(hb, Vb[2], bs[2], (float*)d_out);
    }
  }
}

// Round 11
// 413.504 us; speedup vs baseline: 1.1516x; 1.1516x over previous
//
#include <hip/hip_runtime.h>
#include <stdint.h>

typedef short bf16x8_t __attribute__((ext_vector_type(8)));
typedef short bf16x4_t __attribute__((ext_vector_type(4)));
typedef float f32x4_t __attribute__((ext_vector_type(4)));
typedef unsigned short u16x4_t __attribute__((ext_vector_type(4)));
typedef unsigned short u16x8_t __attribute__((ext_vector_type(8)));

#define DEV static __device__ __forceinline__

DEV float bf2f(unsigned short u) {
  union { unsigned int i; float f; } v; v.i = ((unsigned int)u) << 16; return v.f;
}
DEV unsigned short f2bf(float f) {
  union { float f; unsigned int i; } v; v.f = f;
  unsigned int x = v.i;
  unsigned int lsb = (x >> 16) & 1u;
  x += 0x7fffu + lsb;
  return (unsigned short)(x >> 16);
}

// Up to 3 cvt segments; boundaries in blocks of 256 vec4s (block-uniform).
struct CvtSeg {
  const float* src[3];
  unsigned short* dst[3];
  int bstart[4];   // bstart[0]=0; bstart[3]=total blocks
};

DEV void cvt_block(const CvtSeg& cs, int vb, int tid) {
  int seg = (vb >= cs.bstart[1] ? 1 : 0) + (vb >= cs.bstart[2] ? 1 : 0);
  int local = (vb - cs.bstart[seg]) * 256 + tid;
  float4 v = ((const float4*)cs.src[seg])[local];
  u16x4_t o = { f2bf(v.x), f2bf(v.y), f2bf(v.z), f2bf(v.w) };
  *(u16x4_t*)&cs.dst[seg][local * 4] = o;
}

// ---------------------------------------------------------------------------
// Dispatch 1: xu_fused + appended Wm0 conversion (blockIdx >= 512).
// xu part: converts x (fp32 -> bf16 in xb) AND computes u0 = x @ U0^T,
// reading U0 directly in fp32 (L2-hot, inline-converted) so no serial
// U0-conversion dispatch is needed.
__global__ __launch_bounds__(256, 2) void xu_fused(
    const float* __restrict__ x,            // [8192 x 1024] fp32
    const float* __restrict__ U0f,          // [64 x 1024] fp32
    unsigned short* __restrict__ xb,        // [8192 x 1024] bf16 out
    unsigned short* __restrict__ u_out,     // [8192 x 64] bf16 out
    CvtSeg cs) {                            // appended cvt work (Wm0)
  __shared__ unsigned short tlds[4 * 16 * 72];  // per-wave x chunk [16][72]
  __shared__ float upart[4 * 16 * 68];          // per-wave u partial [16][68]

  if (blockIdx.x >= 512) {                  // appended conversion work
    cvt_block(cs, blockIdx.x - 512, threadIdx.x);
    return;
  }

  const int tid = threadIdx.x;
  const int lane = tid & 63;
  const int w = tid >> 6;
  const int fr = lane & 15;
  const int quad = lane >> 4;
  const int rowBase = blockIdx.x * 16;

  unsigned short* tl = &tlds[w * 16 * 72];
  const int m2 = lane >> 2;          // row within the 16-row block
  const int kc = (lane & 3) * 16;    // 16-col sub-chunk

  f32x4_t uacc[4];
#pragma unroll
  for (int n = 0; n < 4; n++) uacc[n] = f32x4_t{0.f, 0.f, 0.f, 0.f};

  for (int it = 0; it < 4; ++it) {
    const int cb = w * 256 + it * 64;  // k-chunk base

    // load x[16][64] fp32 chunk, convert, stage to LDS + store xb
    {
      const float* xp = x + (size_t)(rowBase + m2) * 1024 + cb + kc;
      float4 v0 = *(const float4*)(xp);
      float4 v1 = *(const float4*)(xp + 4);
      float4 v2 = *(const float4*)(xp + 8);
      float4 v3 = *(const float4*)(xp + 12);
      u16x8_t o0 = { f2bf(v0.x), f2bf(v0.y), f2bf(v0.z), f2bf(v0.w),
                     f2bf(v1.x), f2bf(v1.y), f2bf(v1.z), f2bf(v1.w) };
      u16x8_t o1 = { f2bf(v2.x), f2bf(v2.y), f2bf(v2.z), f2bf(v2.w),
                     f2bf(v3.x), f2bf(v3.y), f2bf(v3.z), f2bf(v3.w) };
      *(u16x8_t*)&tl[m2 * 72 + kc] = o0;
      *(u16x8_t*)&tl[m2 * 72 + kc + 8] = o1;
      unsigned short* xo = xb + (size_t)(rowBase + m2) * 1024 + cb + kc;
      *(u16x8_t*)xo = o0;
      *(u16x8_t*)(xo + 8) = o1;
    }

    // u += x_chunk @ U0^T (K = this 64-col chunk); U0 read fp32 + inline cvt
#pragma unroll
    for (int ks = 0; ks < 2; ++ks) {
      bf16x8_t at = *(const bf16x8_t*)&tl[fr * 72 + ks * 32 + quad * 8];
#pragma unroll
      for (int n = 0; n < 4; n++) {
        const float* up = U0f + (size_t)(n * 16 + fr) * 1024 + cb + ks * 32 +
                          quad * 8;
        float4 uv0 = *(const float4*)(up);
        float4 uv1 = *(const float4*)(up + 4);
        bf16x8_t bu = { (short)f2bf(uv0.x), (short)f2bf(uv0.y),
                        (short)f2bf(uv0.z), (short)f2bf(uv0.w),
                        (short)f2bf(uv1.x), (short)f2bf(uv1.y),
                        (short)f2bf(uv1.z), (short)f2bf(uv1.w) };
        uacc[n] = __builtin_amdgcn_mfma_f32_16x16x32_bf16(at, bu, uacc[n], 0, 0, 0);
      }
    }
  }

  // cross-wave reduction of u partials
  {
    float* up = &upart[w * 16 * 68];
#pragma unroll
    for (int n = 0; n < 4; n++)
#pragma unroll
      for (int r = 0; r < 4; r++)
        up[(quad * 4 + r) * 68 + n * 16 + fr] = uacc[n][r];
  }
  __syncthreads();
  {
    int m = tid >> 4;
    int c0 = (tid & 15) * 4;
    f32x4_t s = {0.f, 0.f, 0.f, 0.f};
#pragma unroll
    for (int wv = 0; wv < 4; wv++)
      s += *(const f32x4_t*)&upart[wv * 16 * 68 + m * 68 + c0];
    u16x4_t o = { f2bf(s[0]), f2bf(s[1]), f2bf(s[2]), f2bf(s[3]) };
    *(u16x4_t*)&u_out[(size_t)(rowBase + m) * 64 + c0] = o;
  }
}

// ---------------------------------------------------------------------------
// Fused hyper-GEMM + per-sample contraction (col' = s*64+r permutation),
// PLUS appended cvt blocks (blockIdx.x >= 2048). 16x16x32 MFMA (r9-verified;
// 32x32x16 regressed — 64-elem LDS rows force bank = slot*4, 4-way conflict).
__global__ __launch_bounds__(256, 2) void k_hyper(
    const unsigned short* __restrict__ A,    // [8192 x 1024] bf16
    const unsigned short* __restrict__ Wmb,  // [4096 x 1024] bf16
    const unsigned short* __restrict__ ug,   // [8192 x 64] bf16
    const float* __restrict__ bm,            // [4096] fp32
    unsigned short* __restrict__ h_out,      // [8192 x 64] bf16
    CvtSeg cs) {
  __shared__ unsigned short smem[16384];

  if (blockIdx.x >= 2048) {                  // appended conversion work
    cvt_block(cs, blockIdx.x - 2048, threadIdx.x);
    return;
  }

  unsigned short* As = smem;
  unsigned short* Bs = smem + 8192;
  const int K = 1024;

  const int tid = threadIdx.x;
  const int lane = tid & 63;
  const int w = tid >> 6;
  const int wrow0 = (w & 1) * 64;
  const int wcol0 = (w >> 1) * 64;
  const int bx = blockIdx.x & 31;
  const int by = blockIdx.x >> 5;
  const int rowBase = by * 128;
  const int colBase = bx * 128;

  const int rl = lane >> 3;
  const int kbg = (lane & 7) ^ rl;
  const int fr = lane & 15;
  const int quad = lane >> 4;

  f32x4_t acc[4][4];
#pragma unroll
  for (int i = 0; i < 4; i++)
#pragma unroll
    for (int j = 0; j < 4; j++) acc[i][j] = f32x4_t{0.f, 0.f, 0.f, 0.f};

  for (int kt = 0; kt < K; kt += 64) {
    __syncthreads();
#pragma unroll
    for (int jj = 0; jj < 4; ++jj) {
      int tr = w * 32 + jj * 8 + rl;
      int ct = colBase + tr;
      int pr = ((ct & 63) << 6) | (ct >> 6);  // Wm row for hyper-col ct
      const unsigned short* ga = A + (size_t)(rowBase + tr) * K + kt + kbg * 8;
      const unsigned short* gb = Wmb + (size_t)pr * K + kt + kbg * 8;
      __builtin_amdgcn_global_load_lds(
          (const __attribute__((address_space(1))) void*)ga,
          (__attribute__((address_space(3))) void*)&As[(w * 32 + jj * 8) * 64],
          16, 0, 0);
      __builtin_amdgcn_global_load_lds(
          (const __attribute__((address_space(1))) void*)gb,
          (__attribute__((address_space(3))) void*)&Bs[(w * 32 + jj * 8) * 64],
          16, 0, 0);
    }
    __syncthreads();

#pragma unroll
    for (int ks = 0; ks < 2; ++ks) {
      bf16x8_t a[4], b[4];
#pragma unroll
      for (int i = 0; i < 4; i++) {
        int m = wrow0 + i * 16 + fr;
        int slot = (ks * 4 + quad) ^ (m & 7);
        a[i] = *(const bf16x8_t*)&As[m * 64 + slot * 8];
      }
#pragma unroll
      for (int j = 0; j < 4; j++) {
        int n = wcol0 + j * 16 + fr;
        int slot = (ks * 4 + quad) ^ (n & 7);
        b[j] = *(const bf16x8_t*)&Bs[n * 64 + slot * 8];
      }
#pragma unroll
      for (int i = 0; i < 4; i++)
#pragma unroll
        for (int j = 0; j < 4; j++)
          acc[i][j] = __builtin_amdgcn_mfma_f32_16x16x32_bf16(a[i], b[j],
                                                              acc[i][j], 0, 0, 0);
    }
  }

  // ---- fused contraction epilogue ----
  __syncthreads();

  // stage u transposed: u_t[r][row], stride 136 to spread banks
  {
    int row = tid >> 1;
    int c0 = (tid & 1) * 32;
    const unsigned short* up = ug + (size_t)(rowBase + row) * 64 + c0;
    bf16x8_t v0 = *(const bf16x8_t*)(up);
    bf16x8_t v1 = *(const bf16x8_t*)(up + 8);
    bf16x8_t v2 = *(const bf16x8_t*)(up + 16);
    bf16x8_t v3 = *(const bf16x8_t*)(up + 24);
#pragma unroll
    for (int m = 0; m < 8; m++) {
      smem[(c0 + m) * 136 + row] = (unsigned short)v0[m];
      smem[(c0 + 8 + m) * 136 + row] = (unsigned short)v1[m];
      smem[(c0 + 16 + m) * 136 + row] = (unsigned short)v2[m];
      smem[(c0 + 24 + m) * 136 + row] = (unsigned short)v3[m];
    }
  }
  __syncthreads();

  const int s = bx * 2 + (w >> 1);
  float bmv[4];
#pragma unroll
  for (int j = 0; j < 4; j++) bmv[j] = bm[(j * 16 + fr) * 64 + s];

#pragma unroll
  for (int i = 0; i < 4; i++) {
    int row0 = wrow0 + i * 16 + quad * 4;
    bf16x4_t uv[4];
#pragma unroll
    for (int j = 0; j < 4; j++)
      uv[j] = *(const bf16x4_t*)&smem[(j * 16 + fr) * 136 + row0];
#pragma unroll
    for (int r = 0; r < 4; r++) {
      float p = 0.f;
#pragma unroll
      for (int j = 0; j < 4; j++)
        p += bf2f((unsigned short)uv[j][r]) * (acc[i][j][r] + bmv[j]);
      p += __shfl_xor(p, 1, 64);
      p += __shfl_xor(p, 2, 64);
      p += __shfl_xor(p, 4, 64);
      p += __shfl_xor(p, 8, 64);
      if (fr == 0)
        h_out[(size_t)(rowBase + row0 + r) * 64 + s] = f2bf(p);
    }
  }
}

// ---------------------------------------------------------------------------
// Fused V-GEMM + next-layer u-GEMM (r4-proven).
__global__ __launch_bounds__(256, 2) void vu_fused(
    const unsigned short* __restrict__ h,    // [8192 x 64] bf16
    const unsigned short* __restrict__ Vb,   // [1024 x 64] bf16
    const float* __restrict__ bias,          // [1024] fp32
    const unsigned short* __restrict__ Un,   // [64 x 1024] bf16 (next U)
    unsigned short* __restrict__ act,        // [8192 x 1024] bf16
    unsigned short* __restrict__ u_out) {    // [8192 x 64] bf16
  __shared__ unsigned short tlds[4 * 16 * 72];
  __shared__ float upart[4 * 16 * 68];

  const int tid = threadIdx.x;
  const int lane = tid & 63;
  const int w = tid >> 6;
  const int fr = lane & 15;
  const int quad = lane >> 4;
  const int rowBase = blockIdx.x * 16;

  unsigned short* tl = &tlds[w * 16 * 72];

  bf16x8_t ah0 = *(const bf16x8_t*)&h[(size_t)(rowBase + fr) * 64 + quad * 8];
  bf16x8_t ah1 = *(const bf16x8_t*)&h[(size_t)(rowBase + fr) * 64 + 32 + quad * 8];

  f32x4_t uacc[4];
#pragma unroll
  for (int n = 0; n < 4; n++) uacc[n] = f32x4_t{0.f, 0.f, 0.f, 0.f};

  for (int it = 0; it < 4; ++it) {
    const int cb = w * 256 + it * 64;

    f32x4_t tacc[4];
#pragma unroll
    for (int nt = 0; nt < 4; nt++) {
      const unsigned short* vrow = Vb + (size_t)(cb + nt * 16 + fr) * 64;
      bf16x8_t b0 = *(const bf16x8_t*)&vrow[quad * 8];
      bf16x8_t b1 = *(const bf16x8_t*)&vrow[32 + quad * 8];
      f32x4_t z = {0.f, 0.f, 0.f, 0.f};
      z = __builtin_amdgcn_mfma_f32_16x16x32_bf16(ah0, b0, z, 0, 0, 0);
      tacc[nt] = __builtin_amdgcn_mfma_f32_16x16x32_bf16(ah1, b1, z, 0, 0, 0);
    }

#pragma unroll
    for (int nt = 0; nt < 4; nt++) {
      float bv = bias[cb + nt * 16 + fr];
#pragma unroll
      for (int r = 0; r < 4; r++) {
        float v = tacc[nt][r] + bv;
        v = v > 0.f ? v : 0.f;
        tl[(quad * 4 + r) * 72 + nt * 16 + fr] = f2bf(v);
      }
    }

    {
      int m2 = lane >> 2;
      int kc = (lane & 3) * 16;
      bf16x8_t t0 = *(const bf16x8_t*)&tl[m2 * 72 + kc];
      bf16x8_t t1 = *(const bf16x8_t*)&tl[m2 * 72 + kc + 8];
      unsigned short* ap = act + (size_t)(rowBase + m2) * 1024 + cb + kc;
      *(bf16x8_t*)ap = t0;
      *(bf16x8_t*)(ap + 8) = t1;
    }

#pragma unroll
    for (int ks = 0; ks < 2; ++ks) {
      bf16x8_t at = *(const bf16x8_t*)&tl[fr * 72 + ks * 32 + quad * 8];
#pragma unroll
      for (int n = 0; n < 4; n++) {
        bf16x8_t bu = *(const bf16x8_t*)&Un[(size_t)(n * 16 + fr) * 1024 + cb +
                                            ks * 32 + quad * 8];
        uacc[n] = __builtin_amdgcn_mfma_f32_16x16x32_bf16(at, bu, uacc[n], 0, 0, 0);
      }
    }
  }

  {
    float* up = &upart[w * 16 * 68];
#pragma unroll
    for (int n = 0; n < 4; n++)
#pragma unroll
      for (int r = 0; r < 4; r++)
        up[(quad * 4 + r) * 68 + n * 16 + fr] = uacc[n][r];
  }
  __syncthreads();
  {
    int m = tid >> 4;
    int c0 = (tid & 15) * 4;
    f32x4_t s = {0.f, 0.f, 0.f, 0.f};
#pragma unroll
    for (int wv = 0; wv < 4; wv++)
      s += *(const f32x4_t*)&upart[wv * 16 * 68 + m * 68 + c0];
    u16x4_t o = { f2bf(s[0]), f2bf(s[1]), f2bf(s[2]), f2bf(s[3]) };
    *(u16x4_t*)&u_out[(size_t)(rowBase + m) * 64 + c0] = o;
  }
}

// ---------------------------------------------------------------------------
// Final layer: out = h @ V^T + b (fp32), K = 64.
__global__ __launch_bounds__(256, 2) void k_final(
    const unsigned short* __restrict__ A, const unsigned short* __restrict__ B,
    const float* __restrict__ bias, float* __restrict__ Cout) {
  __shared__ unsigned short As[128 * 64];
  __shared__ unsigned short Bs[128 * 64];

  const int tid = threadIdx.x;
  const int lane = tid & 63;
  const int w = tid >> 6;
  const int wrow0 = (w & 1) * 64;
  const int wcol0 = (w >> 1) * 64;
  const int rowBase = blockIdx.y * 128;
  const int colBase = blockIdx.x * 128;

  const int rl = lane >> 3;
  const int kbg = (lane & 7) ^ rl;
  const int fr = lane & 15;
  const int quad = lane >> 4;

  f32x4_t acc[4][4];
#pragma unroll
  for (int i = 0; i < 4; i++)
#pragma unroll
    for (int j = 0; j < 4; j++) acc[i][j] = f32x4_t{0.f, 0.f, 0.f, 0.f};

  __syncthreads();
#pragma unroll
  for (int jj = 0; jj < 4; ++jj) {
    int tr = w * 32 + jj * 8 + rl;
    const unsigned short* ga = A + (size_t)(rowBase + tr) * 64 + kbg * 8;
    const unsigned short* gb = B + (size_t)(colBase + tr) * 64 + kbg * 8;
    __builtin_amdgcn_global_load_lds(
        (const __attribute__((address_space(1))) void*)ga,
        (__attribute__((address_space(3))) void*)&As[(w * 32 + jj * 8) * 64],
        16, 0, 0);
    __builtin_amdgcn_global_load_lds(
        (const __attribute__((address_space(1))) void*)gb,
        (__attribute__((address_space(3))) void*)&Bs[(w * 32 + jj * 8) * 64],
        16, 0, 0);
  }
  __syncthreads();

#pragma unroll
  for (int ks = 0; ks < 2; ++ks) {
    bf16x8_t a[4], b[4];
#pragma unroll
    for (int i = 0; i < 4; i++) {
      int m = wrow0 + i * 16 + fr;
      int slot = (ks * 4 + quad) ^ (m & 7);
      a[i] = *(const bf16x8_t*)&As[m * 64 + slot * 8];
    }
#pragma unroll
    for (int j = 0; j < 4; j++) {
      int n = wcol0 + j * 16 + fr;
      int slot = (ks * 4 + quad) ^ (n & 7);
      b[j] = *(const bf16x8_t*)&Bs[n * 64 + slot * 8];
    }
#pragma unroll
    for (int i = 0; i < 4; i++)
#pragma unroll
      for (int j = 0; j < 4; j++)
        acc[i][j] = __builtin_amdgcn_mfma_f32_16x16x32_bf16(a[i], b[j],
                                                            acc[i][j], 0, 0, 0);
  }

#pragma unroll
  for (int j = 0; j < 4; j++) {
    int col = colBase + wcol0 + j * 16 + fr;
    float bv = bias[col];
#pragma unroll
    for (int i = 0; i < 4; i++) {
#pragma unroll
      for (int r = 0; r < 4; r++) {
        int row = rowBase + wrow0 + i * 16 + quad * 4 + r;
        Cout[(size_t)row * 1024 + col] = acc[i][j][r] + bv;
      }
    }
  }
}

// ---------------------------------------------------------------------------
extern "C" void kernel_launch(void* const* d_in, const int* in_sizes, int n_in,
                              void* d_out, int out_size, void* d_ws,
                              size_t ws_size, hipStream_t stream) {
  const float* x = (const float*)d_in[0];
  const float* Wm[3] = {(const float*)d_in[1], (const float*)d_in[6], (const float*)d_in[11]};
  const float* bm[3] = {(const float*)d_in[2], (const float*)d_in[7], (const float*)d_in[12]};
  const float* U[3]  = {(const float*)d_in[3], (const float*)d_in[8], (const float*)d_in[13]};
  const float* V[3]  = {(const float*)d_in[4], (const float*)d_in[9], (const float*)d_in[14]};
  const float* bs[3] = {(const float*)d_in[5], (const float*)d_in[10], (const float*)d_in[15]};

  char* p = (char*)d_ws;
  unsigned short* xb = (unsigned short*)p;  p += 8192UL * 1024 * 2;
  unsigned short* act = (unsigned short*)p; p += 8192UL * 1024 * 2;
  unsigned short* Wmb[3];
  for (int l = 0; l < 3; l++) { Wmb[l] = (unsigned short*)p; p += 4096UL * 1024 * 2; }
  unsigned short* Ub[3];
  for (int l = 0; l < 3; l++) { Ub[l] = (unsigned short*)p; p += 64UL * 1024 * 2; }
  unsigned short* Vb[3];
  for (int l = 0; l < 3; l++) { Vb[l] = (unsigned short*)p; p += 1024UL * 64 * 2; }
  unsigned short* hb = (unsigned short*)p;  p += 8192UL * 64 * 2;
  unsigned short* ug = (unsigned short*)p;  p += 8192UL * 64 * 2;

  // Dispatch 1: xu_fused (x cvt + u0 GEMM, fp32 U0 direct) + Wm0 cvt appended
  CvtSeg c0;
  c0.src[0] = Wm[0]; c0.dst[0] = Wmb[0];
  c0.src[1] = Wm[0]; c0.dst[1] = Wmb[0];  // unused (bstart collapse)
  c0.src[2] = Wm[0]; c0.dst[2] = Wmb[0];  // unused
  c0.bstart[0] = 0; c0.bstart[1] = 4096; c0.bstart[2] = 4096; c0.bstart[3] = 4096;
  xu_fused<<<512 + 4096, 256, 0, stream>>>(x, U[0], xb, ug, c0);

  // cvt tables for the work appended to each hyper dispatch
  CvtSeg ch[3];
  ch[0].src[0] = Wm[1]; ch[0].dst[0] = Wmb[1];
  ch[0].src[1] = U[1];  ch[0].dst[1] = Ub[1];
  ch[0].src[2] = V[0];  ch[0].dst[2] = Vb[0];
  ch[0].bstart[0] = 0; ch[0].bstart[1] = 4096; ch[0].bstart[2] = 4160; ch[0].bstart[3] = 4224;
  ch[1].src[0] = Wm[2]; ch[1].dst[0] = Wmb[2];
  ch[1].src[1] = U[2];  ch[1].dst[1] = Ub[2];
  ch[1].src[2] = V[1];  ch[1].dst[2] = Vb[1];
  ch[1].bstart[0] = 0; ch[1].bstart[1] = 4096; ch[1].bstart[2] = 4160; ch[1].bstart[3] = 4224;
  ch[2].src[0] = V[2]; ch[2].dst[0] = Vb[2];
  ch[2].src[1] = V[2]; ch[2].dst[1] = Vb[2];   // unused
  ch[2].src[2] = V[2]; ch[2].dst[2] = Vb[2];   // unused
  ch[2].bstart[0] = 0; ch[2].bstart[1] = 64; ch[2].bstart[2] = 64; ch[2].bstart[3] = 64;

  const int hyperGrid[3] = {2048 + 4224, 2048 + 4224, 2048 + 64};

  const unsigned short* cur = xb;
  for (int l = 0; l < 3; l++) {
    // fused: h = einsum('br,brs->bs', u, cur@Wm^T + bm)  [+ appended cvt]
    k_hyper<<<hyperGrid[l], 256, 0, stream>>>(cur, Wmb[l], ug, bm[l], hb, ch[l]);
    if (l < 2) {
      // act = relu(h@V^T + b); u(next) = act @ U[l+1]^T
      vu_fused<<<512, 256, 0, stream>>>(hb, Vb[l], bs[l], Ub[l + 1], act, ug);
      cur = act;
    } else {
      k_final<<<dim3(8, 64), 256, 0, stream>>>(hb, Vb[2], bs[2], (float*)d_out);
    }
  }
}